// Round 6
// baseline (3451.307 us; speedup 1.0000x reference)
//
#include <hip/hip_runtime.h>
#include <hip/hip_fp16.h>

// R11: cross-block producer/consumer + fully register-resident Wh scan.
// R7/R10 post-mortem: step is LDS-READ-bound (R10: 288 b128/CU-step ~3460cyc
// of a 4270cyc step; R7: 208). Dominant term = weight frags re-read from LDS
// every step because the 480KB weight set barely exceeds what regs can hold
// WITH the x-GEMM fused. Fix: scan does Wh ONLY (48 frags = 192 regs, all
// resident; LDS traffic 64 reads/CU-step ~770cyc). The x-path ships as gx
// records produced by 224 producer blocks (R6 protocol, HW-proven incl.
// ring-slot reuse) in R9's lane-symmetric layout (producer lane==consumer
// lane, 48B/lane contiguous, coalesced both sides; R9-validated e2e).
// Consumer issues its 3 dwordx4 gx loads at step top, consumes them ~1000cyc
// later -> IC latency hidden (R6's fatal flaw was same-instant use).
// ws >= 25.17MB proven available (R9 ran). Fallback: R7 kernel (1845us).

typedef short v8s __attribute__((ext_vector_type(8)));   // 8 bf16
typedef float f32x4 __attribute__((ext_vector_type(4)));
typedef unsigned int u32x4 __attribute__((ext_vector_type(4)));

#define LOG2E 1.4426950408889634f

__device__ __forceinline__ unsigned short f2b(float f) {
    unsigned int u = __float_as_uint(f);
    u += 0x7FFFu + ((u >> 16) & 1u);       // RNE
    return (unsigned short)(u >> 16);
}
__device__ __forceinline__ float b2f(unsigned short h) {
    return __uint_as_float(((unsigned int)h) << 16);
}
__device__ __forceinline__ unsigned short f2h(float f) {
    return __half_as_ushort(__float2half_rn(f));
}
__device__ __forceinline__ float hxu(unsigned int u, int hi) {
    unsigned short b = (unsigned short)(hi ? (u >> 16) : (u & 0xFFFFu));
    return __half2float(__ushort_as_half(b));
}
__device__ __forceinline__ v8s cvt8(f32x4 a, f32x4 b) {
    v8s r;
#pragma unroll
    for (int j = 0; j < 4; ++j) { r[j] = (short)f2b(a[j]); r[4 + j] = (short)f2b(b[j]); }
    return r;
}
__device__ __forceinline__ v8s wfrag(const float* src, float s) {
    f32x4 a = *(const f32x4*)src, b = *(const f32x4*)(src + 4);
    a *= s; b *= s;
    return cvt8(a, b);
}
__device__ __forceinline__ float rcpf(float v) {
#if __has_builtin(__builtin_amdgcn_rcpf)
    return __builtin_amdgcn_rcpf(v);
#else
    return 1.0f / v;
#endif
}
__device__ __forceinline__ float exp2f_(float v) {
#if __has_builtin(__builtin_amdgcn_exp2f)
    return __builtin_amdgcn_exp2f(v);
#else
    return __exp2f(v);
#endif
}
// sigmoid of log2e-prescaled preactivation (HW-validated R6/R7/R9)
__device__ __forceinline__ float sg(float v) { return rcpf(1.0f + exp2f_(-v)); }
__device__ __forceinline__ f32x4 MF(v8s a, v8s b, f32x4 c) {
    return __builtin_amdgcn_mfma_f32_16x16x32_bf16(a, b, c, 0, 0, 0);
}
// A-frag order index for element (row, k): u16 units
__device__ __forceinline__ int fidx(int row, int k) {
    return ((k >> 5) << 9) + ((((k >> 3) & 3) << 4) + row) * 8 + (k & 7);
}

// LDS: producer wxf 96KB; consumer h ping-pong 16KB (same allocation)
#define LDS11_SIZE 98304

// ctrl (uint): done[0..63], consumed[64..127]; memset 1024B per launch.
extern "C" __global__ void __launch_bounds__(512, 2)
gru_v11(const float* __restrict__ x, const float* __restrict__ Wx,
        const float* __restrict__ Wh, const float* __restrict__ bias,
        const float* __restrict__ fcw, const float* __restrict__ fcb,
        unsigned short* __restrict__ gx, unsigned int* __restrict__ ctrl,
        int n_slots, int cs, float* __restrict__ out)
{
    extern __shared__ char lds[];
    const int tid = threadIdx.x;
    const int w = tid >> 6, l = tid & 63;
    const int cl = l & 15, kg = l >> 4;
    const size_t slot_elems = 393216ull << cs;   // u16 per ring slot
    const int T = 1 << cs;                       // timesteps per chunk
    const int tiles[6] = {2*w, 2*w+1, 16+2*w, 17+2*w, 32+2*w, 33+2*w};

    if (blockIdx.x >= 32) {
        // ---------------- producer: gx records into ring ----------------
        v8s* wxf = (v8s*)lds;                    // 96 frags * 64 * 16B
        const int pid = blockIdx.x - 32;         // 0..223
        const int cs4 = cs - 4;

        for (int fid = w; fid < 96; fid += 8) {
            int ct = fid >> 1, k2 = fid & 1;
            float sc = (ct < 32) ? LOG2E : 2.0f * LOG2E;
            const float* src = Wx + (size_t)(ct * 16 + cl) * 64 + k2 * 32 + kg * 8;
            wxf[fid * 64 + l] = wfrag(src, sc);
        }
        float bv[6];
#pragma unroll
        for (int tt = 0; tt < 6; ++tt)
            bv[tt] = bias[tiles[tt] * 16 + cl] * ((tt < 4) ? LOG2E : 2.0f * LOG2E);
        __syncthreads();

        // jobs: j = tc*32 + g (tc = 16-step group 0..63) -> chunk-ordered
        for (int j = pid; j < 2048; j += 224) {
            const int tc = j >> 5, g = j & 31;
            const int c = tc >> cs4;
            const int b0 = g << 4;
            if (c >= n_slots) {                  // ring slot reuse gate
                if (tid == 0) {
                    while (__hip_atomic_load(&ctrl[64 + (c - n_slots)],
                                             __ATOMIC_ACQUIRE,
                                             __HIP_MEMORY_SCOPE_AGENT) < 32u)
                        __builtin_amdgcn_s_sleep(16);
                }
                __syncthreads();
            }
            unsigned short* gxs = gx + (size_t)(c % n_slots) * slot_elems;
            const int tl0 = (tc << 4) - (c << cs);

            for (int t16 = 0; t16 < 16; ++t16) {
                const int t = (tc << 4) + t16;
                const int tl = tl0 + t16;
                const float* xs = x + ((size_t)(b0 + cl) * 1024 + t) * 64 + kg * 8;
                v8s a0 = cvt8(*(const f32x4*)xs,        *(const f32x4*)(xs + 4));
                v8s a1 = cvt8(*(const f32x4*)(xs + 32), *(const f32x4*)(xs + 36));

                f32x4 acc[6];
#pragma unroll
                for (int tt = 0; tt < 6; ++tt)
                    acc[tt] = f32x4{bv[tt], bv[tt], bv[tt], bv[tt]};
#pragma unroll
                for (int tt = 0; tt < 6; ++tt) {
                    acc[tt] = MF(a0, wxf[(tiles[tt] * 2) * 64 + l], acc[tt]);
                    acc[tt] = MF(a1, wxf[(tiles[tt] * 2 + 1) * 64 + l], acc[tt]);
                }
                // lane-symmetric record: this lane's 24 values = consumer
                // lane (w,l) of block g's record (R9-validated layout)
                unsigned int q[12];
#pragma unroll
                for (int tt = 0; tt < 6; ++tt) {
                    q[tt*2]   = (unsigned int)f2h(acc[tt][0]) | ((unsigned int)f2h(acc[tt][1]) << 16);
                    q[tt*2+1] = (unsigned int)f2h(acc[tt][2]) | ((unsigned int)f2h(acc[tt][3]) << 16);
                }
                unsigned int* gp = (unsigned int*)
                    (gxs + ((size_t)((g << cs) + tl)) * 12288 + (size_t)tid * 24);
                u32x4 s0 = {q[0], q[1], q[2],  q[3]};
                u32x4 s1 = {q[4], q[5], q[6],  q[7]};
                u32x4 s2 = {q[8], q[9], q[10], q[11]};
                *(u32x4*)(gp)     = s0;
                *(u32x4*)(gp + 4) = s1;
                *(u32x4*)(gp + 8) = s2;
            }
            __syncthreads();                     // all waves' stores drained
            if (tid == 0)
                __hip_atomic_fetch_add(&ctrl[c], 1u, __ATOMIC_RELEASE,
                                       __HIP_MEMORY_SCOPE_AGENT);
        }
        return;
    }

    // ---------------- consumer: pure-Wh register-resident scan ----------------
    char* hl = lds;                              // 16KB h ping-pong
    const int g = blockIdx.x;
    const int b0 = g << 4;

    // ALL six Wh tiles register-resident (48 frags = 192 regs)
    v8s whB[6][8];
#pragma unroll
    for (int tt = 0; tt < 6; ++tt) {
        const float sc = (tt < 4) ? LOG2E : 2.0f * LOG2E;
        const float* src = Wh + (size_t)(tiles[tt] * 16 + cl) * 256 + kg * 8;
#pragma unroll
        for (int ks = 0; ks < 8; ++ks)
            whB[tt][ks] = wfrag(src + ks * 32, sc);
    }
    float brv[2], bzv[2];
#pragma unroll
    for (int p = 0; p < 2; ++p) {
        const int ch = (w << 5) + (p << 4) + cl;
        brv[p] = bias[ch] * LOG2E;
        bzv[p] = bias[256 + ch] * LOG2E;
    }

    for (int i = tid; i < 2048; i += 512) ((unsigned int*)hl)[i] = 0u;  // h0=0
    float hprev[8] = {0, 0, 0, 0, 0, 0, 0, 0};

    const unsigned jobs_pc = 32u << (cs - 4);
    const int nch = 1024 >> cs;
    int t = 0;
    for (int c = 0; c < nch; ++c) {
        if (tid == 0) {
            while (__hip_atomic_load(&ctrl[c], __ATOMIC_ACQUIRE,
                                     __HIP_MEMORY_SCOPE_AGENT) < jobs_pc)
                __builtin_amdgcn_s_sleep(16);
        }
        // first step's __syncthreads orders the spin vs all lanes' gx loads
        const unsigned short* gq0 = gx + (size_t)(c % n_slots) * slot_elems
                                   + ((size_t)(g << cs)) * 12288 + (size_t)tid * 24;

        for (int tl = 0; tl < T; ++tl, ++t) {
            __syncthreads();
            const int cur = t & 1;
            const v8s* hb = (const v8s*)(hl + cur * 8192);

            // gx record: 3 coalesced dwordx4, issued now, consumed post-MFMA
            const u32x4* gq = (const u32x4*)(gq0 + (size_t)tl * 12288);
            u32x4 gr = gq[0], gz = gq[1], gn = gq[2];

            f32x4 aR[2], aZ[2], aN[2];
            aR[0] = f32x4{brv[0], brv[0], brv[0], brv[0]};
            aR[1] = f32x4{brv[1], brv[1], brv[1], brv[1]};
            aZ[0] = f32x4{bzv[0], bzv[0], bzv[0], bzv[0]};
            aZ[1] = f32x4{bzv[1], bzv[1], bzv[1], bzv[1]};
            aN[0] = f32x4{0, 0, 0, 0};
            aN[1] = f32x4{0, 0, 0, 0};

#pragma unroll
            for (int ks = 0; ks < 8; ++ks) {
                v8s a = hb[(ks << 6) + l];
                aR[0] = MF(a, whB[0][ks], aR[0]);
                aR[1] = MF(a, whB[1][ks], aR[1]);
                aZ[0] = MF(a, whB[2][ks], aZ[0]);
                aZ[1] = MF(a, whB[3][ks], aZ[1]);
                aN[0] = MF(a, whB[4][ks], aN[0]);
                aN[1] = MF(a, whB[5][ks], aN[1]);
            }

            unsigned short* hn = (unsigned short*)(hl + (cur ^ 1) * 8192);
#pragma unroll
            for (int p = 0; p < 2; ++p) {
                const int ch = (w << 5) + (p << 4) + cl;
                const int chbase = ((ch >> 5) << 9) + (((ch >> 3) & 3) << 7) + (ch & 7);
#pragma unroll
                for (int i = 0; i < 4; ++i) {
                    const int dw = p * 2 + (i >> 1), hi = i & 1;
                    float rg = sg(aR[p][i] + hxu(gr[dw], hi));
                    float zg = sg(aZ[p][i] + hxu(gz[dw], hi));
                    float nv = __builtin_fmaf(rg, aN[p][i], hxu(gn[dw], hi));
                    float ng = __builtin_fmaf(2.0f, sg(nv), -1.0f);
                    float hy = ng + zg * (hprev[p * 4 + i] - ng);
                    hprev[p * 4 + i] = hy;
                    hn[chbase + ((kg << 2) + i) * 8] = f2b(hy);
                }
            }
        }
        __syncthreads();                         // chunk's gx loads all done
        if (tid == 0)
            __hip_atomic_fetch_add(&ctrl[64 + c], 1u, __ATOMIC_RELEASE,
                                   __HIP_MEMORY_SCOPE_AGENT);
    }

    __syncthreads();
    // logits from hT (buffer 0 after 1024 steps)
    const unsigned short* hf = (const unsigned short*)hl;
    if (tid < 160) {
        int row = tid / 10, cls = tid - row * 10;
        float s = fcb[cls];
        const float* wrow = fcw + cls * 256;
        for (int k = 0; k < 256; ++k)
            s += b2f(hf[fidx(row, k)]) * wrow[k];
        out[(b0 + row) * 10 + cls] = s;
    }
}

// ================= fallback (ws too small): R7 kernel, proven 1845us =================
#define LDS7_H    131072
#define LDS7_X    147456
#define LDS7_SIZE 151552

extern "C" __global__ void __launch_bounds__(512, 2)
gru_v7(const float* __restrict__ x, const float* __restrict__ Wx,
       const float* __restrict__ Wh, const float* __restrict__ bias,
       const float* __restrict__ fcw, const float* __restrict__ fcb,
       float* __restrict__ out)
{
    extern __shared__ char lds[];
    v8s* whn = (v8s*)lds;
    char* hl = lds + LDS7_H;
    char* xl = lds + LDS7_X;

    const int tid = threadIdx.x;
    const int w = tid >> 6, l = tid & 63;
    const int cl = l & 15, kg = l >> 4;
    const int b0 = blockIdx.x << 4;
    const int tiles[6] = {2*w, 2*w+1, 16+2*w, 17+2*w, 32+2*w, 33+2*w};

    for (int f = w; f < 128; f += 8) {
        int t5 = f >> 3, ks = f & 7;
        const float* src = Wh + (size_t)(512 + t5*16 + cl)*256 + ks*32 + kg*8;
        whn[f*64 + l] = wfrag(src, 2.0f*LOG2E);
    }
    v8s whB[4][8];
#pragma unroll
    for (int tt = 0; tt < 4; ++tt) {
        const float* src = Wh + (size_t)(tiles[tt]*16 + cl)*256 + kg*8;
#pragma unroll
        for (int ks = 0; ks < 8; ++ks)
            whB[tt][ks] = wfrag(src + ks*32, LOG2E);
    }
    v8s wxr[12];
#pragma unroll
    for (int tt = 0; tt < 6; ++tt) {
        const float sc = (tt < 4) ? LOG2E : 2.0f*LOG2E;
        const float* s0 = Wx + (size_t)(tiles[tt]*16 + cl)*64 + kg*8;
        wxr[tt*2]   = wfrag(s0, sc);
        wxr[tt*2+1] = wfrag(s0 + 32, sc);
    }
    float brv[2], bzv[2], bhv[2];
#pragma unroll
    for (int p = 0; p < 2; ++p) {
        int ch = (w << 5) + (p << 4) + cl;
        brv[p] = bias[ch] * LOG2E;
        bzv[p] = bias[256 + ch] * LOG2E;
        bhv[p] = bias[512 + ch] * 2.0f*LOG2E;
    }
    for (int i = tid; i < 2048; i += 512) ((unsigned int*)hl)[i] = 0u;
    float hprev[8] = {0, 0, 0, 0, 0, 0, 0, 0};
    const int xr = tid >> 5, xc = (tid & 31) << 1;
    const int xidx = fidx(xr, xc);
    const float* xp = x + (((size_t)(b0 + xr)) << 16) + xc;
    {
        unsigned int pk = (unsigned int)f2b(xp[0]) | ((unsigned int)f2b(xp[1]) << 16);
        *(unsigned int*)(xl + xidx*2) = pk;
    }
    xp += 64;
    const int wn0 = (2*w)*8, wn1 = (2*w+1)*8;

    for (int t = 0; t < 1024; ++t) {
        __syncthreads();
        const int cur = t & 1;
        const v8s* hb = (const v8s*)(hl + cur*8192);
        const v8s* xb = (const v8s*)(xl + cur*2048);
        float xv0 = 0.0f, xv1 = 0.0f;
        if (t < 1023) { xv0 = xp[0]; xv1 = xp[1]; xp += 64; }

        f32x4 acc[8];
        acc[0] = f32x4{brv[0], brv[0], brv[0], brv[0]};
        acc[1] = f32x4{brv[1], brv[1], brv[1], brv[1]};
        acc[2] = f32x4{bzv[0], bzv[0], bzv[0], bzv[0]};
        acc[3] = f32x4{bzv[1], bzv[1], bzv[1], bzv[1]};
        acc[4] = f32x4{0, 0, 0, 0};
        acc[5] = f32x4{0, 0, 0, 0};
        acc[6] = f32x4{bhv[0], bhv[0], bhv[0], bhv[0]};
        acc[7] = f32x4{bhv[1], bhv[1], bhv[1], bhv[1]};
#pragma unroll
        for (int ks = 0; ks < 8; ++ks) {
            v8s a  = hb[(ks << 6) + l];
            v8s n0 = whn[(wn0 + ks)*64 + l];
            v8s n1 = whn[(wn1 + ks)*64 + l];
            acc[0] = MF(a, whB[0][ks], acc[0]);
            acc[1] = MF(a, whB[1][ks], acc[1]);
            acc[2] = MF(a, whB[2][ks], acc[2]);
            acc[3] = MF(a, whB[3][ks], acc[3]);
            acc[4] = MF(a, n0, acc[4]);
            acc[5] = MF(a, n1, acc[5]);
        }
#pragma unroll
        for (int k2 = 0; k2 < 2; ++k2) {
            v8s ax = xb[(k2 << 6) + l];
            acc[0] = MF(ax, wxr[0  + k2], acc[0]);
            acc[1] = MF(ax, wxr[2  + k2], acc[1]);
            acc[2] = MF(ax, wxr[4  + k2], acc[2]);
            acc[3] = MF(ax, wxr[6  + k2], acc[3]);
            acc[6] = MF(ax, wxr[8  + k2], acc[6]);
            acc[7] = MF(ax, wxr[10 + k2], acc[7]);
        }
        unsigned short* hn = (unsigned short*)(hl + (cur ^ 1) * 8192);
#pragma unroll
        for (int p = 0; p < 2; ++p) {
            const int ch = (w << 5) + (p << 4) + cl;
            const int chbase = ((ch >> 5) << 9) + (((ch >> 3) & 3) << 7) + (ch & 7);
#pragma unroll
            for (int i = 0; i < 4; ++i) {
                float rg = sg(acc[p][i]);
                float zg = sg(acc[2 + p][i]);
                float nv = __builtin_fmaf(rg, acc[4 + p][i], acc[6 + p][i]);
                float ng = __builtin_fmaf(2.0f, sg(nv), -1.0f);
                float hy = ng + zg * (hprev[p*4 + i] - ng);
                hprev[p*4 + i] = hy;
                hn[chbase + ((kg << 2) + i) * 8] = f2b(hy);
            }
        }
        if (t < 1023) {
            unsigned int pk = (unsigned int)f2b(xv0) | ((unsigned int)f2b(xv1) << 16);
            *(unsigned int*)(xl + ((cur ^ 1) * 2048) + xidx*2) = pk;
        }
    }

    __syncthreads();
    const unsigned short* hf = (const unsigned short*)hl;
    if (tid < 160) {
        int row = tid / 10, cls = tid - row * 10;
        float s = fcb[cls];
        const float* wrow = fcw + cls * 256;
        for (int k = 0; k < 256; ++k)
            s += b2f(hf[fidx(row, k)]) * wrow[k];
        out[(b0 + row)*10 + cls] = s;
    }
}

extern "C" void kernel_launch(void* const* d_in, const int* in_sizes, int n_in,
                              void* d_out, int out_size, void* d_ws, size_t ws_size,
                              hipStream_t stream) {
    const float* x    = (const float*)d_in[0];
    const float* Wx   = (const float*)d_in[1];
    const float* Wh   = (const float*)d_in[2];
    const float* bias = (const float*)d_in[3];
    const float* fcw  = (const float*)d_in[4];
    const float* fcb  = (const float*)d_in[5];

    // pick largest chunk (64/32/16 timesteps) with >=2 ring slots in ws
    int cs = -1, n_slots = 0;
    for (int s = 6; s >= 4; --s) {
        unsigned long long slot = 786432ull << s;     // bytes per slot
        if (ws_size < 1024ull + 2ull * slot) continue;
        int nch = 1024 >> s;
        unsigned long long n = (ws_size - 1024ull) / slot;
        n_slots = (n > (unsigned long long)nch) ? nch : (int)n;
        cs = s;
        break;
    }

    if (cs >= 4) {
        unsigned int* ctrl =
            (unsigned int*)((char*)d_ws + (786432ull << cs) * (size_t)n_slots);
        (void)hipMemsetAsync(ctrl, 0, 1024, stream);
        (void)hipFuncSetAttribute((const void*)gru_v11,
                                  hipFuncAttributeMaxDynamicSharedMemorySize, LDS11_SIZE);
        gru_v11<<<dim3(256), dim3(512), LDS11_SIZE, stream>>>(
            x, Wx, Wh, bias, fcw, fcb,
            (unsigned short*)d_ws, ctrl, n_slots, cs, (float*)d_out);
    } else {
        (void)hipFuncSetAttribute((const void*)gru_v7,
                                  hipFuncAttributeMaxDynamicSharedMemorySize, LDS7_SIZE);
        gru_v7<<<dim3(32), dim3(512), LDS7_SIZE, stream>>>(
            x, Wx, Wh, bias, fcw, fcb, (float*)d_out);
    }
}

// Round 7
// 2994.717 us; speedup vs baseline: 1.1525x; 1.1525x over previous
//
#include <hip/hip_runtime.h>
#include <hip/hip_fp16.h>

// R12: all-register Wh scan + ON-CHIP (LDS) chunked gx prepass, one block/batch-tile.
// R6/R9/R11 post-mortem: every off-chip gx transport loses ~1-4ms to HBM/IC
// latency. R11's consumer proved all-6-Wh-tiles-in-regs works (AGPR file,
// VGPR_Count=128). R12 produces gx IN LDS by the same block: per 4-step
// chunk: [A] x->LDS A-frags; [P] 3 passes x 2 gate-tiles of x-GEMM writing
// 48B lane-local records (producer lane == consumer lane, R9-validated
// layout; stride-48 b128 = bank-uniform ~2-way, free per m136); [S] 4 scan
// steps: h (8 b128) + record (3 b128) + 48 MFMA + epilogue. Weight LDS
// traffic: ZERO. Per-CU-step LDS ~110 b128 (R7: 208). Bias folded ONLY in
// prepass (R11's double-bias fixed). No workspace, no cross-block sync.

typedef short v8s __attribute__((ext_vector_type(8)));   // 8 bf16
typedef float f32x4 __attribute__((ext_vector_type(4)));
typedef unsigned int u32x4 __attribute__((ext_vector_type(4)));

#define LOG2E 1.4426950408889634f
#define CHUNK 4
#define NCH   256
#define REC   48                 // bytes per (t,tid) gx record
#define GXT   (512 * REC)        // 24576 B per timestep

// LDS: h ping-pong 16384 | x A-frags 4t*2048=8192 | gx 4t*24576=98304
#define L_H    0
#define L_XF   16384
#define L_GX   24576
#define LDS_SZ 122880

__device__ __forceinline__ unsigned short f2b(float f) {
    unsigned int u = __float_as_uint(f);
    u += 0x7FFFu + ((u >> 16) & 1u);       // RNE
    return (unsigned short)(u >> 16);
}
__device__ __forceinline__ float b2f(unsigned short h) {
    return __uint_as_float(((unsigned int)h) << 16);
}
__device__ __forceinline__ unsigned int pkh(float a, float b) {
    return (unsigned int)__half_as_ushort(__float2half_rn(a))
         | ((unsigned int)__half_as_ushort(__float2half_rn(b)) << 16);
}
__device__ __forceinline__ float hxu(unsigned int u, int hi) {
    unsigned short b = (unsigned short)(hi ? (u >> 16) : (u & 0xFFFFu));
    return __half2float(__ushort_as_half(b));
}
__device__ __forceinline__ v8s cvt8(f32x4 a, f32x4 b) {
    v8s r;
#pragma unroll
    for (int j = 0; j < 4; ++j) { r[j] = (short)f2b(a[j]); r[4 + j] = (short)f2b(b[j]); }
    return r;
}
__device__ __forceinline__ v8s wfrag(const float* src, float s) {
    f32x4 a = *(const f32x4*)src, b = *(const f32x4*)(src + 4);
    a *= s; b *= s;
    return cvt8(a, b);
}
__device__ __forceinline__ float rcpf(float v) {
#if __has_builtin(__builtin_amdgcn_rcpf)
    return __builtin_amdgcn_rcpf(v);
#else
    return 1.0f / v;
#endif
}
__device__ __forceinline__ float exp2f_(float v) {
#if __has_builtin(__builtin_amdgcn_exp2f)
    return __builtin_amdgcn_exp2f(v);
#else
    return __exp2f(v);
#endif
}
// sigmoid of log2e-prescaled preactivation (HW-validated R6/R7/R9)
__device__ __forceinline__ float sg(float v) { return rcpf(1.0f + exp2f_(-v)); }
__device__ __forceinline__ f32x4 MF(v8s a, v8s b, f32x4 c) {
    return __builtin_amdgcn_mfma_f32_16x16x32_bf16(a, b, c, 0, 0, 0);
}
// A-frag order index for element (row, k): u16 units
__device__ __forceinline__ int fidx(int row, int k) {
    return ((k >> 5) << 9) + ((((k >> 3) & 3) << 4) + row) * 8 + (k & 7);
}

extern "C" __global__ void __launch_bounds__(512, 2)
gru_v12(const float* __restrict__ x, const float* __restrict__ Wx,
        const float* __restrict__ Wh, const float* __restrict__ bias,
        const float* __restrict__ fcw, const float* __restrict__ fcb,
        float* __restrict__ out)
{
    extern __shared__ char lds[];
    char* hl = lds + L_H;
    unsigned short* xf = (unsigned short*)(lds + L_XF);
    char* gxl = lds + L_GX;

    const int tid = threadIdx.x;
    const int w = tid >> 6, l = tid & 63;
    const int cl = l & 15, kg = l >> 4;
    const int b0 = blockIdx.x << 4;
    const int tiles[6] = {2*w, 2*w+1, 16+2*w, 17+2*w, 32+2*w, 33+2*w};

    // ALL six Wh tiles register/AGPR-resident (48 frags), prescaled
    v8s whB[6][8];
#pragma unroll
    for (int tt = 0; tt < 6; ++tt) {
        const float sc = (tt < 4) ? LOG2E : 2.0f * LOG2E;
        const float* src = Wh + (size_t)(tiles[tt] * 16 + cl) * 256 + kg * 8;
#pragma unroll
        for (int ks = 0; ks < 8; ++ks)
            whB[tt][ks] = wfrag(src + ks * 32, sc);
    }
    // prescaled bias for prepass (folded ONLY here — R11 double-bias fixed)
    float bv6[6];
#pragma unroll
    for (int tt = 0; tt < 6; ++tt)
        bv6[tt] = bias[tiles[tt] * 16 + cl] * ((tt < 4) ? LOG2E : 2.0f * LOG2E);

    // h0 = 0 (buffer 0)
    for (int i = tid; i < 2048; i += 512) ((unsigned int*)hl)[i] = 0u;
    float hprev[8] = {0, 0, 0, 0, 0, 0, 0, 0};

    // phase-A thread mapping: 8 floats (one A-frag octet) per thread
    const int a_tl = tid >> 7;             // 0..3 timestep in chunk
    const int a_rm = tid & 127;
    const int a_r  = a_rm >> 3;            // 0..15 batch row
    const int a_k0 = (a_rm & 7) << 3;      // 0,8,..,56
    unsigned short* const a_dst = xf + a_tl * 1024 + fidx(a_r, a_k0);
    const float* const a_src = x + (size_t)(b0 + a_r) * 65536 + a_k0;

    // per-thread gx record base
    char* const my_rec = gxl + tid * REC;
    const int chbase0 = ((w << 5) + cl);   // p=0 channel

    for (int c = 0; c < NCH; ++c) {
        const int c0 = c << 2;

        // ---------- A: stage chunk's x as MFMA A-frags ----------
        {
            const float* xs = a_src + (size_t)(c0 + a_tl) * 64;
            *(v8s*)a_dst = cvt8(*(const f32x4*)xs, *(const f32x4*)(xs + 4));
        }
        __syncthreads();

        // ---------- P: gx records, 3 passes x 2 gate-tiles ----------
#pragma unroll
        for (int ps = 0; ps < 3; ++ps) {
            const float sc = (ps < 2) ? LOG2E : 2.0f * LOG2E;
            const int ta = tiles[ps * 2], tb = tiles[ps * 2 + 1];
            const float* wsa = Wx + (size_t)(ta * 16 + cl) * 64 + kg * 8;
            const float* wsb = Wx + (size_t)(tb * 16 + cl) * 64 + kg * 8;
            v8s wa0 = wfrag(wsa, sc), wa1 = wfrag(wsa + 32, sc);
            v8s wb0 = wfrag(wsb, sc), wb1 = wfrag(wsb + 32, sc);
            const float ba = bv6[ps * 2], bb = bv6[ps * 2 + 1];
            const v8s* xv = (const v8s*)xf;
#pragma unroll
            for (int tl = 0; tl < CHUNK; ++tl) {
                v8s a0 = xv[tl * 128 + l];
                v8s a1 = xv[tl * 128 + 64 + l];
                f32x4 aa = {ba, ba, ba, ba}, ab = {bb, bb, bb, bb};
                aa = MF(a0, wa0, aa); aa = MF(a1, wa1, aa);
                ab = MF(a0, wb0, ab); ab = MF(a1, wb1, ab);
                u32x4 s = {pkh(aa[0], aa[1]), pkh(aa[2], aa[3]),
                           pkh(ab[0], ab[1]), pkh(ab[2], ab[3])};
                *(u32x4*)(my_rec + tl * GXT + ps * 16) = s;
            }
        }

        // ---------- S: scan 4 steps, pure register Wh ----------
#pragma unroll
        for (int tl = 0; tl < CHUNK; ++tl) {
            const int t = c0 + tl;
            __syncthreads();               // h ping-pong + gx records ready
            const int cur = t & 1;
            const v8s* hb = (const v8s*)(hl + cur * 8192);

            // own gx record: 3 b128 LDS reads (stride-48 = bank-uniform)
            const u32x4* gq = (const u32x4*)(my_rec + tl * GXT);
            u32x4 gr = gq[0], gz = gq[1], gn = gq[2];

            f32x4 aR[2], aZ[2], aN[2];
            aR[0] = f32x4{0, 0, 0, 0}; aR[1] = f32x4{0, 0, 0, 0};
            aZ[0] = f32x4{0, 0, 0, 0}; aZ[1] = f32x4{0, 0, 0, 0};
            aN[0] = f32x4{0, 0, 0, 0}; aN[1] = f32x4{0, 0, 0, 0};

#pragma unroll
            for (int ks = 0; ks < 8; ++ks) {
                v8s a = hb[(ks << 6) + l];
                aR[0] = MF(a, whB[0][ks], aR[0]);
                aR[1] = MF(a, whB[1][ks], aR[1]);
                aZ[0] = MF(a, whB[2][ks], aZ[0]);
                aZ[1] = MF(a, whB[3][ks], aZ[1]);
                aN[0] = MF(a, whB[4][ks], aN[0]);
                aN[1] = MF(a, whB[5][ks], aN[1]);
            }

            unsigned short* hn = (unsigned short*)(hl + (cur ^ 1) * 8192);
#pragma unroll
            for (int p = 0; p < 2; ++p) {
                const int ch = chbase0 + (p << 4);
                const int chbase = ((ch >> 5) << 9) + (((ch >> 3) & 3) << 7) + (ch & 7);
#pragma unroll
                for (int i = 0; i < 4; ++i) {
                    const int dw = p * 2 + (i >> 1), hi = i & 1;
                    float rg = sg(aR[p][i] + hxu(gr[dw], hi));
                    float zg = sg(aZ[p][i] + hxu(gz[dw], hi));
                    float nv = __builtin_fmaf(rg, aN[p][i], hxu(gn[dw], hi));
                    float ng = __builtin_fmaf(2.0f, sg(nv), -1.0f);
                    float hy = ng + zg * (hprev[p * 4 + i] - ng);
                    hprev[p * 4 + i] = hy;
                    hn[chbase + ((kg << 2) + i) * 8] = f2b(hy);
                }
            }
        }
        __syncthreads();                   // scan's xf/gxl reads done before next A/P
    }

    __syncthreads();
    // logits from hT (buffer 0 after 1024 steps)
    const unsigned short* hf = (const unsigned short*)hl;
    if (tid < 160) {
        int row = tid / 10, cls = tid - row * 10;
        float s = fcb[cls];
        const float* wrow = fcw + cls * 256;
        for (int k = 0; k < 256; ++k)
            s += b2f(hf[fidx(row, k)]) * wrow[k];
        out[(b0 + row) * 10 + cls] = s;
    }
}

extern "C" void kernel_launch(void* const* d_in, const int* in_sizes, int n_in,
                              void* d_out, int out_size, void* d_ws, size_t ws_size,
                              hipStream_t stream) {
    const float* x    = (const float*)d_in[0];
    const float* Wx   = (const float*)d_in[1];
    const float* Wh   = (const float*)d_in[2];
    const float* bias = (const float*)d_in[3];
    const float* fcw  = (const float*)d_in[4];
    const float* fcb  = (const float*)d_in[5];
    (void)d_ws; (void)ws_size;

    (void)hipFuncSetAttribute((const void*)gru_v12,
                              hipFuncAttributeMaxDynamicSharedMemorySize, LDS_SZ);
    gru_v12<<<dim3(32), dim3(512), LDS_SZ, stream>>>(
        x, Wx, Wh, bias, fcw, fcb, (float*)d_out);
}